// Round 9
// baseline (572.050 us; speedup 1.0000x reference)
//
#include <hip/hip_runtime.h>
#include <hip/hip_bf16.h>
#include <stdint.h>

typedef __hip_bfloat16 bf16;
typedef __attribute__((ext_vector_type(8))) short short8;
typedef __attribute__((ext_vector_type(4))) float f32x4;

__device__ __forceinline__ bf16 f2b(float x) { return __float2bfloat16(x); }

#define NW 8

// ---- LDS map (bytes) ----
// conv0: A0w[0..81312) X[81312..127392) BS[151712..161952)
// pre1 : A0r A1w[81312..151712) BS
// pre2 : A1r A2w[0..57024) BS
// pre3 : A2r[0..57024) Zring w[57024..114048) B3[114048..150912)
// post : Zring r/w, Bpost[0..55296) (dead A2)
// final: Yf32[0..86016), last conv
#define A0_OFF 0
#define X_OFF  81312
#define A1_OFF 81312
#define A2_OFF 0
#define Z_OFF  57024
#define B3_OFF 114048     // 2 x 18432
#define BS_OFF 151712     // 2 x 5120
#define BP_OFF 0          // buf0 [0..30720) taps0-4, buf1 [30720..55296) taps5-8
#define YF_OFF 0
#define SMEM_SZ 161952

__device__ __forceinline__ void gload_lds16(const void* g, char* l) {
    __builtin_amdgcn_global_load_lds(
        (const __attribute__((address_space(1))) unsigned int*)g,
        (__attribute__((address_space(3))) unsigned int*)l, 16, 0, 0);
}

// DPP 16-lane-row shifts with zero bound (the SAME-conv zero border).
// dx=0 operand: lane r takes lane r-1 (row_shr:1). dx=2: lane r+1 (row_shl:1).
__device__ __forceinline__ short8 dpp_sr1(short8 v) {
    union { short8 s; int i[4]; } a, o;
    a.s = v;
#pragma unroll
    for (int q = 0; q < 4; ++q)
        o.i[q] = __builtin_amdgcn_mov_dpp(a.i[q], 0x111, 0xf, 0xf, true);
    return o.s;
}
__device__ __forceinline__ short8 dpp_sl1(short8 v) {
    union { short8 s; int i[4]; } a, o;
    a.s = v;
#pragma unroll
    for (int q = 0; q < 4; ++q)
        o.i[q] = __builtin_amdgcn_mov_dpp(a.i[q], 0x101, 0xf, 0xf, true);
    return o.s;
}

// ---------------------------------------------------------------------------
__global__ __launch_bounds__(1024) void topk_kernel(const float* __restrict__ err,
                                                    float* __restrict__ ref_out,
                                                    int* __restrict__ sel)
{
    __shared__ uint64_t keys[4096];
    const int b = blockIdx.x >> 4, slice = blockIdx.x & 15;
    const float* e = err + b * 4096;
    for (int t = threadIdx.x; t < 4096; t += 1024) {
        uint32_t u = __float_as_uint(e[t]);
        u ^= (u >> 31) ? 0xFFFFFFFFu : 0x80000000u;
        keys[t] = ((uint64_t)u << 32) | (uint32_t)(4095 - t);
    }
    __syncthreads();
    const int cand = slice * 256 + (threadIdx.x >> 2);
    const int part = threadIdx.x & 3;
    const uint64_t mykey = keys[cand];
    int r = 0;
#pragma unroll 8
    for (int j = part * 1024; j < part * 1024 + 1024; ++j)
        r += (keys[j] > mykey) ? 1 : 0;
    r += __shfl_xor(r, 1);
    r += __shfl_xor(r, 2);
    if (part == 0) {
        bool s = (r < 512);
        if (s) sel[b * 512 + r] = cand;
        ref_out[b * 4096 + cand] = (s && e[cand] > 0.f) ? 1.f : 0.f;
    }
}

// ---------------------------------------------------------------------------
// Weight prepack (bf16, zero-padded k>=C_in and co>=80):
//  l0   @0       elems: [tap][n5][lane][8]              (23040)
//  l1,2 @23040 : [tap][kb][n5][lane][8]                 (69120 each)
//  l3   @161280: [tap][kb][n6][lane][8]                 (82944)   N=96
//  post @244224: [kb][tap][n6][lane][8] x7              (82944 each) N=96
//  + wlastT[tap][ci] f32, bnprep[l][co96][{inv,beta}] f32
// ---------------------------------------------------------------------------
__global__ void wt_kernel(const float* __restrict__ w0, const float* __restrict__ wpre,
                          const float* __restrict__ wpost, const float* __restrict__ w_last,
                          const float* __restrict__ bn0, const float* __restrict__ bn_pre,
                          const float* __restrict__ bn_post,
                          bf16* __restrict__ Wf, float* __restrict__ wlastT,
                          float* __restrict__ bnprep)
{
    int t = blockIdx.x * blockDim.x + threadIdx.x;
    if (t < 824832) {
        int co, k, tap;
        float v = 0.f;
        if (t < 23040) {
            tap = t / 2560; int rem = t % 2560;
            int n = rem / 512, r2 = rem % 512, lane = r2 / 8, i = r2 % 8;
            co = n * 16 + (lane & 15); k = (lane >> 4) * 8 + i;
            if (k < 31) v = w0[(co * 31 + k) * 9 + tap];
        } else if (t < 161280) {
            int t2 = t - 23040;
            int l = t2 / 69120;                 // 0,1 -> wpre layer 0,1
            int r0 = t2 % 69120;
            tap = r0 / 7680; int r1 = r0 % 7680;
            int kb = r1 / 2560, rem = r1 % 2560;
            int n = rem / 512, r2 = rem % 512, lane = r2 / 8, i = r2 % 8;
            co = n * 16 + (lane & 15); k = kb * 32 + (lane >> 4) * 8 + i;
            if (k < 80) v = wpre[((l * 80 + co) * 80 + k) * 9 + tap];
        } else if (t < 244224) {
            int t3 = t - 161280;                // pre3 = wpre layer 2, N=96
            tap = t3 / 9216; int r0 = t3 % 9216;
            int kb = r0 / 3072, rem = r0 % 3072;
            int n = rem / 512, r2 = rem % 512, lane = r2 / 8, i = r2 % 8;
            co = n * 16 + (lane & 15); k = kb * 32 + (lane >> 4) * 8 + i;
            if (co < 80 && k < 80) v = wpre[((2 * 80 + co) * 80 + k) * 9 + tap];
        } else {
            int t4 = t - 244224;                // post layers, [kb][tap][n6]
            int l = t4 / 82944; int r0 = t4 % 82944;
            int kb = r0 / 27648; int r1 = r0 % 27648;
            tap = r1 / 3072; int rem = r1 % 3072;
            int n = rem / 512, r2 = rem % 512, lane = r2 / 8, i = r2 % 8;
            co = n * 16 + (lane & 15); k = kb * 32 + (lane >> 4) * 8 + i;
            if (co < 80 && k < 80) v = wpost[((l * 80 + co) * 80 + k) * 9 + tap];
        }
        Wf[t] = f2b(v);
    } else if (t < 825552) {
        int i = t - 824832; int tap = i / 80, ci = i % 80;
        wlastT[tap * 80 + ci] = w_last[ci * 9 + tap];
    } else if (t < 826608) {
        int i = t - 825552; int l = i / 96, co = i % 96;
        float inv = 0.f, beta = 0.f;
        if (co < 80) {
            const float* src = (l == 0) ? bn0 : (l <= 3 ? bn_pre + (l - 1) * 320
                                                        : bn_post + (l - 4) * 320);
            float g = src[co], bb = src[80 + co], m = src[160 + co], vv = src[240 + co];
            inv = g * rsqrtf(vv + 1e-5f);
            beta = bb - m * inv;
        }
        bnprep[i * 2] = inv; bnprep[i * 2 + 1] = beta;
    }
}

// ---------------------------------------------------------------------------
__global__ void copy_kernel(const uint4* __restrict__ src, uint4* __restrict__ dst, int n)
{
    int t = blockIdx.x * blockDim.x + threadIdx.x;
    if (t < n) dst[t] = src[t];
}

// ---------------------------------------------------------------------------
// conv0/pre1/pre2 (VALID, N=80, partition 2m x 5n): R8-proven structure.
// ---------------------------------------------------------------------------
template <int NIN, int NOUT, int KB, int ISTR, int OSTR>
__device__ __forceinline__ void conv_small(char* sm, int inBase, int outBase,
                                           const char* __restrict__ Wl,
                                           const float* __restrict__ bnl)
{
    const int tid = threadIdx.x;
    const int wv = tid >> 6, lane = tid & 63;
    const int r = lane & 15, kg = lane >> 4;
    constexpr int NPIX = NOUT * NOUT;
    constexpr int NMT = (NPIX + 15) / 16;
    constexpr int NSTEP = 9 * KB;

    int aA[2][2];
    bool act[2][2];
#pragma unroll
    for (int pp = 0; pp < 2; ++pp)
#pragma unroll
        for (int mm = 0; mm < 2; ++mm) {
            int mt = (wv + pp * NW) * 2 + mm;
            int pix = mt * 16 + r;
            act[pp][mm] = (mt < NMT);
            int cp = pix < NPIX ? pix : NPIX - 1;
            aA[pp][mm] = inBase + ((cp / NOUT) * NIN + cp % NOUT) * ISTR + kg * 16;
        }

    float invb[5], betb[5];
#pragma unroll
    for (int n = 0; n < 5; ++n) {
        float2 v = ((const float2*)bnl)[n * 16 + r];
        invb[n] = v.x; betb[n] = v.y;
    }

    f32x4 zz = {0.f, 0.f, 0.f, 0.f};
    f32x4 acc[2][2][5];
#pragma unroll
    for (int pp = 0; pp < 2; ++pp)
#pragma unroll
        for (int mm = 0; mm < 2; ++mm)
#pragma unroll
            for (int n = 0; n < 5; ++n) acc[pp][mm][n] = zz;

    auto stage = [&](int step) {
        if (tid < 320)
            gload_lds16(Wl + step * 5120 + tid * 16,
                        sm + BS_OFF + (step & 1) * 5120 + tid * 16);
    };

    stage(0);
    __syncthreads();

#pragma unroll
    for (int s = 0; s < NSTEP; ++s) {
        if (s + 1 < NSTEP) stage(s + 1);
        const int tap = s / KB, kb = s % KB;
        const int dtap = (tap / 3) * NIN + (tap % 3);
        const int sb = BS_OFF + (s & 1) * 5120;
        short8 bf[5];
#pragma unroll
        for (int n = 0; n < 5; ++n)
            bf[n] = *(const short8*)(sm + sb + n * 1024 + lane * 16);
#pragma unroll
        for (int pp = 0; pp < 2; ++pp)
#pragma unroll
            for (int mm = 0; mm < 2; ++mm) {
                if (!act[pp][mm]) continue;
                short8 af = *(const short8*)(sm + aA[pp][mm] + dtap * ISTR + kb * 64);
#pragma unroll
                for (int n = 0; n < 5; ++n)
                    acc[pp][mm][n] = __builtin_amdgcn_mfma_f32_16x16x32_bf16(
                        af, bf[n], acc[pp][mm][n], 0, 0, 0);
            }
        __syncthreads();
    }

#pragma unroll
    for (int pp = 0; pp < 2; ++pp)
#pragma unroll
        for (int mm = 0; mm < 2; ++mm) {
            int mt = (wv + pp * NW) * 2 + mm;
            if (mt < NMT) {
#pragma unroll
                for (int n = 0; n < 5; ++n) {
                    int co = n * 16 + r;
#pragma unroll
                    for (int j = 0; j < 4; ++j) {
                        int pix = mt * 16 + kg * 4 + j;
                        if (pix < NPIX) {
                            float o = fmaxf(acc[pp][mm][n][j] * invb[n] + betb[n], 0.f);
                            *(bf16*)(sm + outBase + pix * OSTR + co * 2) = f2b(o);
                        }
                    }
                }
            }
        }
}

// ---------------------------------------------------------------------------
// pre3: VALID 18->16, partition 4m x 3n, N=96, tap-dbuf staging.
// Fills Yreg and the zero-bordered Z ring (18x18, stride 176B).
// ---------------------------------------------------------------------------
__device__ __forceinline__ void pre3_conv(char* sm, const char* __restrict__ Wl,
                                          const float* __restrict__ bnl,
                                          f32x4 (&Yreg)[4][3])
{
    const int tid = threadIdx.x;
    const int wv = tid >> 6, lane = tid & 63;
    const int r = lane & 15, kg = lane >> 4;
    const int wm = wv & 3, wn = wv >> 2;

    float invb[3], betb[3];
#pragma unroll
    for (int n = 0; n < 3; ++n) {
        float2 v = ((const float2*)bnl)[(3 * wn + n) * 16 + r];
        invb[n] = v.x; betb[n] = v.y;
    }

    f32x4 zz = {0.f, 0.f, 0.f, 0.f};
    f32x4 acc[4][3];
#pragma unroll
    for (int mm = 0; mm < 4; ++mm)
#pragma unroll
        for (int n = 0; n < 3; ++n) acc[mm][n] = zz;

    auto stage = [&](int tap) {
        const char* src = Wl + tap * 18432;
        char* dst = sm + B3_OFF + (tap & 1) * 18432;
#pragma unroll
        for (int it = 0; it < 3; ++it) {
            int off = it * 8192 + tid * 16;
            if (off < 18432) gload_lds16(src + off, dst + off);
        }
    };

    stage(0);
    __syncthreads();

#pragma unroll
    for (int tap = 0; tap < 9; ++tap) {
        if (tap + 1 < 9) stage(tap + 1);
        const int dy = tap / 3, dx = tap % 3;
        const int slotB = B3_OFF + (tap & 1) * 18432;
#pragma unroll
        for (int kb = 0; kb < 3; ++kb) {
            short8 bf[3];
#pragma unroll
            for (int n = 0; n < 3; ++n)
                bf[n] = *(const short8*)(sm + slotB + (kb * 6 + 3 * wn + n) * 1024 + lane * 16);
#pragma unroll
            for (int mm = 0; mm < 4; ++mm) {
                short8 af = *(const short8*)(sm + A2_OFF +
                    ((4 * wm + mm + dy) * 18 + r + dx) * 176 + kb * 64 + kg * 16);
#pragma unroll
                for (int n = 0; n < 3; ++n)
                    acc[mm][n] = __builtin_amdgcn_mfma_f32_16x16x32_bf16(
                        af, bf[n], acc[mm][n], 0, 0, 0);
            }
        }
        __syncthreads();
    }

#pragma unroll
    for (int mm = 0; mm < 4; ++mm)
#pragma unroll
        for (int n = 0; n < 3; ++n) {
            int co = (3 * wn + n) * 16 + r;
            bool keep = (3 * wn + n) < 5;
            int y = 4 * wm + mm;
#pragma unroll
            for (int j = 0; j < 4; ++j) {
                int x = kg * 4 + j;
                float o = fmaxf(acc[mm][n][j] * invb[n] + betb[n], 0.f);
                Yreg[mm][n][j] = o;
                if (keep)
                    *(bf16*)(sm + Z_OFF + ((y + 1) * 18 + x + 1) * 176 + co * 2) = f2b(o);
            }
        }
}

// ---------------------------------------------------------------------------
// post layer: SAME over Z ring, partition 4m x 3n, N=96, kb-outer,
// A centers cached + DPP-derived dx operands, half-slice B staging.
// ---------------------------------------------------------------------------
template <int LAST>
__device__ __forceinline__ void post_layer(char* sm, const char* __restrict__ Wl,
                                           const float* __restrict__ bnl,
                                           f32x4 (&Yreg)[4][3])
{
    const int tid = threadIdx.x;
    const int wv = tid >> 6, lane = tid & 63;
    const int r = lane & 15, kg = lane >> 4;
    const int wm = wv & 3, wn = wv >> 2;

    float invb[3], betb[3];
#pragma unroll
    for (int n = 0; n < 3; ++n) {
        float2 v = ((const float2*)bnl)[(3 * wn + n) * 16 + r];
        invb[n] = v.x; betb[n] = v.y;
    }

    f32x4 zz = {0.f, 0.f, 0.f, 0.f};
    f32x4 acc[4][3];
#pragma unroll
    for (int mm = 0; mm < 4; ++mm)
#pragma unroll
        for (int n = 0; n < 3; ++n) acc[mm][n] = zz;

    auto fill0 = [&](int kb) {   // taps 0..4, 30720B
#pragma unroll
        for (int it = 0; it < 4; ++it) {
            int off = it * 8192 + tid * 16;
            if (off < 30720) gload_lds16(Wl + kb * 55296 + off, sm + BP_OFF + off);
        }
    };
    auto fill1 = [&](int kb) {   // taps 5..8, 24576B exact
#pragma unroll
        for (int it = 0; it < 3; ++it) {
            int off = it * 8192 + tid * 16;
            gload_lds16(Wl + kb * 55296 + 30720 + off, sm + BP_OFF + 30720 + off);
        }
    };

    const int cBase = Z_OFF + (4 * wm * 18 + 1 + r) * 176 + kg * 16;

    fill0(0);
    __syncthreads();

#pragma unroll
    for (int kb = 0; kb < 3; ++kb) {
        short8 C[6];
#pragma unroll
        for (int u = 0; u < 6; ++u)
            C[u] = *(const short8*)(sm + cBase + u * 3168 + kb * 64);

        // phase A: taps 0..4 on buf0, fill buf1
        fill1(kb);
#pragma unroll
        for (int tap = 0; tap < 5; ++tap) {
            const int dy = tap / 3, dx = tap % 3;
            short8 bf[3];
#pragma unroll
            for (int n = 0; n < 3; ++n)
                bf[n] = *(const short8*)(sm + BP_OFF + tap * 6144 + (3 * wn + n) * 1024 + lane * 16);
#pragma unroll
            for (int mm = 0; mm < 4; ++mm) {
                short8 af = C[mm + dy];
                if (dx == 0) af = dpp_sr1(af);
                else if (dx == 2) af = dpp_sl1(af);
#pragma unroll
                for (int n = 0; n < 3; ++n)
                    acc[mm][n] = __builtin_amdgcn_mfma_f32_16x16x32_bf16(
                        af, bf[n], acc[mm][n], 0, 0, 0);
            }
        }
        __syncthreads();

        // phase B: taps 5..8 on buf1, fill buf0 for next kb
        if (kb < 2) fill0(kb + 1);
#pragma unroll
        for (int tap = 5; tap < 9; ++tap) {
            const int dy = tap / 3, dx = tap % 3;
            short8 bf[3];
#pragma unroll
            for (int n = 0; n < 3; ++n)
                bf[n] = *(const short8*)(sm + BP_OFF + 30720 + (tap - 5) * 6144 + (3 * wn + n) * 1024 + lane * 16);
#pragma unroll
            for (int mm = 0; mm < 4; ++mm) {
                short8 af = C[mm + dy];
                if (dx == 0) af = dpp_sr1(af);
                else if (dx == 2) af = dpp_sl1(af);
#pragma unroll
                for (int n = 0; n < 3; ++n)
                    acc[mm][n] = __builtin_amdgcn_mfma_f32_16x16x32_bf16(
                        af, bf[n], acc[mm][n], 0, 0, 0);
            }
        }
        __syncthreads();
    }

#pragma unroll
    for (int mm = 0; mm < 4; ++mm)
#pragma unroll
        for (int n = 0; n < 3; ++n) {
            int co = (3 * wn + n) * 16 + r;
            bool keep = (3 * wn + n) < 5;
            int y = 4 * wm + mm;
#pragma unroll
            for (int j = 0; j < 4; ++j) {
                int x = kg * 4 + j;
                float o = fmaxf(acc[mm][n][j] * invb[n] + betb[n], 0.f);
                float nv = Yreg[mm][n][j] + o;
                Yreg[mm][n][j] = nv;
                if (!LAST && keep)
                    *(bf16*)(sm + Z_OFF + ((y + 1) * 18 + x + 1) * 176 + co * 2) = f2b(nv);
            }
        }
}

// ---------------------------------------------------------------------------
__global__ __launch_bounds__(512, 2) void refine_kernel(
    const int* __restrict__ sel,
    const float* __restrict__ hid, const float* __restrict__ pha,
    const char* __restrict__ Wf, const float* __restrict__ wlastT,
    const float* __restrict__ bnprep, float* __restrict__ out)
{
    __shared__ __align__(16) char sm[SMEM_SZ];
    const int tid = threadIdx.x;
    const int p = blockIdx.x;
    const int e = sel[p];
    const int b = p >> 9;
    const int pi = e >> 6, pj = e & 63;

    // zero-fill LDS once (stale-data safety)
    {
        uint4 z4 = {0u, 0u, 0u, 0u};
        uint4* z = (uint4*)sm;
        for (int t = tid; t < SMEM_SZ / 16; t += 512) z[t] = z4;
    }
    __syncthreads();

    // gather X[576 pix][ch31] bf16, 80B rows
    const int r0 = pi * 16 - 4, c0 = pj * 16 - 4;
    for (int t = tid; t < 32 * 576; t += 512) {
        int c = t / 576, pix = t - c * 576;
        int gr = r0 + pix / 24, gc = c0 + pix % 24;
        float v = 0.f;
        if (c < 31 && (unsigned)gr < 1024u && (unsigned)gc < 1024u)
            v = (c < 30) ? hid[((b * 30 + c) * 1024 + gr) * 1024 + gc]
                         : pha[(b * 1024 + gr) * 1024 + gc];
        *(bf16*)(sm + X_OFF + pix * 80 + c * 2) = f2b(v);
    }

    conv_small<24, 22, 1,  80, 168>(sm, X_OFF,  A0_OFF, Wf,          bnprep);
    conv_small<22, 20, 3, 168, 176>(sm, A0_OFF, A1_OFF, Wf + 46080,  bnprep + 192);
    conv_small<20, 18, 3, 176, 176>(sm, A1_OFF, A2_OFF, Wf + 184320, bnprep + 384);

    // zero Z-ring border (68 cells x 176B); published by pre3's first barrier
    for (int t = tid; t < 68 * 11; t += 512) {
        int cell = t / 11, part = t % 11;
        int i, j;
        if (cell < 18)      { i = 0;  j = cell; }
        else if (cell < 36) { i = 17; j = cell - 18; }
        else { int k = cell - 36; i = 1 + (k >> 1); j = (k & 1) ? 17 : 0; }
        *(uint4*)(sm + Z_OFF + (i * 18 + j) * 176 + part * 16) = (uint4){0u, 0u, 0u, 0u};
    }

    f32x4 Yreg[4][3];
    pre3_conv(sm, Wf + 322560, bnprep + 576, Yreg);

#pragma unroll 1
    for (int l = 0; l < 6; ++l)
        post_layer<0>(sm, Wf + 488448 + l * 165888, bnprep + 768 + l * 192, Yreg);
    post_layer<1>(sm, Wf + 488448 + 6 * 165888, bnprep + 768 + 6 * 192, Yreg);

    // spill Y trunk (f32, stride 336B)
    {
        const int wv = tid >> 6, lane = tid & 63;
        const int r = lane & 15, kg = lane >> 4;
        const int wm = wv & 3, wn = wv >> 2;
#pragma unroll
        for (int mm = 0; mm < 4; ++mm)
#pragma unroll
            for (int n = 0; n < 3; ++n) {
                int co = (3 * wn + n) * 16 + r;
                if ((3 * wn + n) < 5) {
#pragma unroll
                    for (int j = 0; j < 4; ++j) {
                        int pix = (4 * wm + mm) * 16 + kg * 4 + j;
                        *(float*)(sm + YF_OFF + pix * 336 + co * 4) = Yreg[mm][n][j];
                    }
                }
            }
    }
    __syncthreads();

    // last conv 80->1 SAME; 2 threads per pixel
    {
        int pix = tid >> 1, half = tid & 1;
        int y = pix >> 4, x = pix & 15;
        float accv = 0.f;
        const float* Yb = (const float*)(sm + YF_OFF);
#pragma unroll
        for (int tap = 0; tap < 9; ++tap) {
            int iy = y + tap / 3 - 1, ix = x + tap % 3 - 1;
            if ((unsigned)iy >= 16u || (unsigned)ix >= 16u) continue;
            const float* yp = Yb + (iy * 16 + ix) * 84;
            const float* wp = wlastT + tap * 80;
            for (int c = half * 40; c < half * 40 + 40; c += 4) {
                float4 a  = *(const float4*)(yp + c);
                float4 w4 = *(const float4*)(wp + c);
                accv += a.x * w4.x + a.y * w4.y + a.z * w4.z + a.w * w4.w;
            }
        }
        accv += __shfl_xor(accv, 1);
        if (half == 0)
            out[b * 1048576 + (pi * 16 + y) * 1024 + pj * 16 + x] = accv;
    }
}

// ---------------------------------------------------------------------------
extern "C" void kernel_launch(void* const* d_in, const int* in_sizes, int n_in,
                              void* d_out, int out_size, void* d_ws, size_t ws_size,
                              hipStream_t stream)
{
    (void)in_sizes; (void)n_in; (void)out_size; (void)ws_size;
    const float* pha     = (const float*)d_in[0];
    const float* err     = (const float*)d_in[1];
    const float* hid     = (const float*)d_in[2];
    const float* w0      = (const float*)d_in[3];
    const float* bn0     = (const float*)d_in[4];
    const float* w_pre   = (const float*)d_in[5];
    const float* bn_pre  = (const float*)d_in[6];
    const float* w_post  = (const float*)d_in[7];
    const float* bn_post = (const float*)d_in[8];
    const float* w_last  = (const float*)d_in[9];
    float* out = (float*)d_out;

    char* ws = (char*)d_ws;
    bf16*  Wf     = (bf16*)ws;                 // 824832 bf16 = 1,649,664 B
    float* wlastT = (float*)(ws + 1649664);    // 720 f32
    float* bnprep = (float*)(ws + 1652544);    // 2112 f32
    int*   sel    = (int*)(ws + 1661056);      // 1024 int

    hipLaunchKernelGGL(wt_kernel, dim3(3230), dim3(256), 0, stream,
                       w0, w_pre, w_post, w_last, bn0, bn_pre, bn_post,
                       Wf, wlastT, bnprep);
    hipLaunchKernelGGL(topk_kernel, dim3(32), dim3(1024), 0, stream,
                       err, out + 2097152, sel);
    hipLaunchKernelGGL(copy_kernel, dim3(2048), dim3(256), 0, stream,
                       (const uint4*)pha, (uint4*)out, 524288);
    hipLaunchKernelGGL(refine_kernel, dim3(1024), dim3(512), 0, stream,
                       sel, hid, pha, (const char*)Wf, wlastT, bnprep, out);
}